// Round 2
// baseline (2587.966 us; speedup 1.0000x reference)
//
#include <hip/hip_runtime.h>
#include <math.h>

#define N_NODES 100000
#define N_FEAT  256
#define K_SEL   50000
#define N_EDGES 3200000
#define NBUCKET 65536
#define NBLK    1024                 /* persistent grid: 4 blocks/CU x 256 CUs */
#define NTHR    256
#define CHUNK_BITS 6                 /* 64 bins per chunk, NBLK chunks */

#define GATHER_VB (K_SEL / 4)        /* 4 rows (64 lanes ea) per 256-thr virtual block */
#define EDGE_VB   (N_EDGES / (4 * 256)) /* 4 edges per thread */

typedef float __attribute__((ext_vector_type(4))) floatx4;
typedef int   __attribute__((ext_vector_type(4))) intx4;

// ---- key encodings -------------------------------------------------------
// ascending uint64 key == descending z, so stable-ascending == top_k order
__device__ __forceinline__ unsigned long long descKey(double z) {
    unsigned long long u = (unsigned long long)__double_as_longlong(z);
    unsigned long long a = (u >> 63) ? ~u : (u | 0x8000000000000000ULL);
    return ~a;
}

// exact inverse of descKey (bit-exact roundtrip, finite values)
__device__ __forceinline__ double invKey(unsigned long long k) {
    unsigned long long a = ~k;
    unsigned long long u = (a >> 63) ? (a & 0x7FFFFFFFFFFFFFFFULL) : ~a;
    return __longlong_as_double((long long)u);
}

__device__ __forceinline__ unsigned int bucketOfFloat(float zf) {
    unsigned int u = __float_as_uint(zf);
    unsigned int a = (u >> 31) ? ~u : (u | 0x80000000u);
    return (~a) >> 16;
}

// ---- device-scope grid barrier ------------------------------------------
// Safe by occupancy arithmetic: NBLK=1024 blocks, __launch_bounds__(256,4)
// => 4 blocks/CU co-resident on 256 CUs. atomicAdd is device-scope;
// __threadfence() on all threads after release handles cross-XCD L2.
__device__ __forceinline__ void gridBarrier(unsigned int* c, unsigned int target) {
    __syncthreads();
    if (threadIdx.x == 0) {
        __threadfence();
        __hip_atomic_fetch_add(c, 1u, __ATOMIC_RELEASE, __HIP_MEMORY_SCOPE_AGENT);
        while (__hip_atomic_load(c, __ATOMIC_ACQUIRE, __HIP_MEMORY_SCOPE_AGENT) < target)
            __builtin_amdgcn_s_sleep(2);
    }
    __syncthreads();
    __threadfence();     /* acquire: drop stale L1/L2 lines before reading peers' data */
    __syncthreads();
}

// ---- the whole pipeline in one persistent kernel -------------------------
__global__ void __launch_bounds__(NTHR, 4)
mega_kernel(const float* __restrict__ x, const int* __restrict__ ei,
            const float* __restrict__ w, float* __restrict__ out,
            double* __restrict__ normp,
            unsigned long long* __restrict__ key64,
            unsigned long long* __restrict__ slotKey,
            int* __restrict__ slotIdx, int* __restrict__ mapping,
            int* __restrict__ perm, float* __restrict__ selDot,
            int* __restrict__ hist, int* __restrict__ start,
            int* __restrict__ chunkSums, int* __restrict__ chunkOff,
            unsigned int* __restrict__ counter) {
    const int blk = blockIdx.x;
    const int t   = threadIdx.x;
    const int gtid = blk * NTHR + t;
    __shared__ double sd[256];
    __shared__ int ss[256];

    // ---- P0: zero hist; block 0 computes ||w|| in fp64 -------------------
    for (int h = gtid; h < NBUCKET; h += NBLK * NTHR) hist[h] = 0;
    if (blk == 0) {
        double v = (double)w[t];
        sd[t] = v * v;
        __syncthreads();
        for (int off = 128; off > 0; off >>= 1) {
            if (t < off) sd[t] += sd[t + off];
            __syncthreads();
        }
        if (t == 0) normp[0] = sqrt(sd[0]);
    }
    gridBarrier(counter, 1 * NBLK);

    // ---- P1: score. one wave per row, grid-stride; fp64 accumulate ------
    {
        const int wid  = gtid >> 6;                 /* 0..4095 */
        const int lane = t & 63;
        const float4 wv = ((const float4*)w)[lane];
        for (int row = wid; row < N_NODES; row += (NBLK * NTHR) >> 6) {
            const float4 xv = ((const float4*)(x + (size_t)row * N_FEAT))[lane];
            double acc = (double)xv.x * (double)wv.x + (double)xv.y * (double)wv.y +
                         (double)xv.z * (double)wv.z + (double)xv.w * (double)wv.w;
            for (int m = 32; m >= 1; m >>= 1) acc += __shfl_xor(acc, m, 64);
            if (lane == 0) {
                key64[row] = descKey(acc);
                atomicAdd(&hist[bucketOfFloat((float)acc)], 1);
            }
        }
    }
    gridBarrier(counter, 2 * NBLK);

    // ---- P2: per-chunk local scan (64 bins/chunk, chunk == block) --------
    if (t < 64) {
        int b = (blk << CHUNK_BITS) + t;
        int v = hist[b];
        int incl = v;
        for (int off = 1; off < 64; off <<= 1) {
            int n = __shfl_up(incl, off, 64);
            if (t >= off) incl += n;
        }
        start[b] = incl - v;                      /* chunk-local exclusive */
        if (t == 63) chunkSums[blk] = incl;       /* chunk total */
    }
    gridBarrier(counter, 3 * NBLK);

    // ---- P3: block 0 scans the 1024 chunk totals -> chunkOff -------------
    if (blk == 0) {
        int4 v = ((const int4*)chunkSums)[t];
        int s = v.x + v.y + v.z + v.w;
        ss[t] = s;
        __syncthreads();
        for (int off = 1; off < 256; off <<= 1) {
            int add = (t >= off) ? ss[t - off] : 0;
            __syncthreads();
            ss[t] += add;
            __syncthreads();
        }
        int run = (t == 0) ? 0 : ss[t - 1];
        int4 o;
        o.x = run; run += v.x;
        o.y = run; run += v.y;
        o.z = run; run += v.z;
        o.w = run;
        ((int4*)chunkOff)[t] = o;
    }
    gridBarrier(counter, 4 * NBLK);

    // ---- P4: scatter nodes to bucket slot ranges -------------------------
    for (int i = gtid; i < N_NODES; i += NBLK * NTHR) {
        unsigned long long k = key64[i];
        float df = (float)invKey(k);
        int b = (int)bucketOfFloat(df);
        int pos = atomicAdd(&start[b], 1) + chunkOff[b >> CHUNK_BITS];
        slotKey[pos] = k;
        slotIdx[pos] = i;
    }
    gridBarrier(counter, 5 * NBLK);

    // ---- P5: exact rank within bucket ------------------------------------
    for (int s = gtid; s < N_NODES; s += NBLK * NTHR) {
        unsigned long long myKey = slotKey[s];
        int i = slotIdx[s];
        float df = (float)invKey(myKey);
        int b = (int)bucketOfFloat(df);
        int end = start[b] + chunkOff[b >> CHUNK_BITS];
        int cnt = hist[b];
        int st = end - cnt;
        if (st >= K_SEL) {                        /* whole bucket below cutoff */
            mapping[i] = -1;
            continue;
        }
        int rank = 0;
        if (cnt > 1) {
            for (int q = st; q < end; ++q) {
                unsigned long long k = slotKey[q];
                if (k < myKey || (k == myKey && slotIdx[q] < i)) ++rank;
            }
        }
        int p = st + rank;
        if (p < K_SEL) {
            mapping[i] = p;
            perm[p] = i;
            selDot[p] = df;
        } else {
            mapping[i] = -1;
        }
    }
    gridBarrier(counter, 6 * NBLK);

    // ---- P6: output. gather+gate rows (tanh here), then edge remap -------
    {
        const float fnorm = (float)normp[0];
        float* oeu = out + (size_t)K_SEL * N_FEAT;
        float* oev = oeu + N_EDGES;
        for (int vb = blk; vb < GATHER_VB + EDGE_VB; vb += NBLK) {
            if (vb < GATHER_VB) {
                int tid = vb * NTHR + t;
                int r = tid >> 6;
                int c = (tid & 63) << 2;
                int src = perm[r];
                float sc = tanhf(selDot[r] / fnorm);
                float4 v = *(const float4*)(x + (size_t)src * N_FEAT + c);
                floatx4 o;
                o.x = v.x * sc; o.y = v.y * sc; o.z = v.z * sc; o.w = v.w * sc;
                __builtin_nontemporal_store(o, (floatx4*)(out + (size_t)r * N_FEAT + c));
            } else {
                int tid = (vb - GATHER_VB) * NTHR + t;
                int e = tid << 2;
                intx4 a = __builtin_nontemporal_load((const intx4*)(ei + e));
                intx4 b = __builtin_nontemporal_load((const intx4*)(ei + N_EDGES + e));
                int m0 = mapping[a.x], m1 = mapping[a.y], m2 = mapping[a.z], m3 = mapping[a.w];
                int n0 = mapping[b.x], n1 = mapping[b.y], n2 = mapping[b.z], n3 = mapping[b.w];
                floatx4 ou, ov;
                bool v0 = (m0 >= 0) && (n0 >= 0);
                bool v1 = (m1 >= 0) && (n1 >= 0);
                bool v2 = (m2 >= 0) && (n2 >= 0);
                bool v3 = (m3 >= 0) && (n3 >= 0);
                ou.x = v0 ? (float)m0 : -1.0f; ov.x = v0 ? (float)n0 : -1.0f;
                ou.y = v1 ? (float)m1 : -1.0f; ov.y = v1 ? (float)n1 : -1.0f;
                ou.z = v2 ? (float)m2 : -1.0f; ov.z = v2 ? (float)n2 : -1.0f;
                ou.w = v3 ? (float)m3 : -1.0f; ov.w = v3 ? (float)n3 : -1.0f;
                __builtin_nontemporal_store(ou, (floatx4*)(oeu + e));
                __builtin_nontemporal_store(ov, (floatx4*)(oev + e));
            }
        }
    }
}

// ---- launch --------------------------------------------------------------
extern "C" void kernel_launch(void* const* d_in, const int* in_sizes, int n_in,
                              void* d_out, int out_size, void* d_ws, size_t ws_size,
                              hipStream_t stream) {
    const float* x  = (const float*)d_in[0];
    const int*   ei = (const int*)d_in[1];
    const float* w  = (const float*)d_in[2];
    float* out = (float*)d_out;

    char* p = (char*)d_ws;
    double* d_norm = (double*)p;                          p += 16;
    unsigned long long* key64   = (unsigned long long*)p; p += (size_t)N_NODES * 8;
    unsigned long long* slotKey = (unsigned long long*)p; p += (size_t)N_NODES * 8;
    int*   mapping = (int*)p;   p += (size_t)N_NODES * 4;
    int*   slotIdx = (int*)p;   p += (size_t)N_NODES * 4;
    int*   perm    = (int*)p;   p += (size_t)K_SEL * 4;
    float* selDot  = (float*)p; p += (size_t)K_SEL * 4;
    int*   hist    = (int*)p;   p += (size_t)NBUCKET * 4;
    int*   start   = (int*)p;   p += (size_t)NBUCKET * 4;
    int*   chunkSums = (int*)p; p += (size_t)NBLK * 4;
    int*   chunkOff  = (int*)p; p += (size_t)NBLK * 4;
    unsigned int* counter = (unsigned int*)p; p += 16;

    /* workspace is poisoned each iteration: barrier counter must start at 0 */
    hipMemsetAsync(counter, 0, sizeof(unsigned int), stream);

    mega_kernel<<<NBLK, NTHR, 0, stream>>>(x, ei, w, out, d_norm, key64, slotKey,
                                           slotIdx, mapping, perm, selDot, hist,
                                           start, chunkSums, chunkOff, counter);
}

// Round 3
// 337.669 us; speedup vs baseline: 7.6642x; 7.6642x over previous
//
#include <hip/hip_runtime.h>
#include <math.h>

#define N_NODES 100000
#define N_FEAT  256
#define K_SEL   50000
#define N_EDGES 3200000
#define NBUCKET 65536
#define NCHUNK  256                         /* NBUCKET / 256 bins per chunk */

#define GATHER_BLOCKS (K_SEL / 4)           /* 4 rows (64 lanes ea) per 256-thr block */
#define EDGE_BLOCKS   (N_EDGES / (4 * 256)) /* 4 edges per thread */

typedef float __attribute__((ext_vector_type(4))) floatx4;
typedef int   __attribute__((ext_vector_type(4))) intx4;

// ---- key encodings -------------------------------------------------------
// ascending uint64 key == descending z, so stable-ascending == top_k order
__device__ __forceinline__ unsigned long long descKey(double z) {
    unsigned long long u = (unsigned long long)__double_as_longlong(z);
    unsigned long long a = (u >> 63) ? ~u : (u | 0x8000000000000000ULL);
    return ~a;
}

// exact inverse of descKey (bit-exact roundtrip, finite values)
__device__ __forceinline__ double invKey(unsigned long long k) {
    unsigned long long a = ~k;
    unsigned long long u = (a >> 63) ? (a & 0x7FFFFFFFFFFFFFFFULL) : ~a;
    return __longlong_as_double((long long)u);
}

__device__ __forceinline__ unsigned int bucketOfFloat(float zf) {
    unsigned int u = __float_as_uint(zf);
    unsigned int a = (u >> 31) ? ~u : (u | 0x80000000u);
    return (~a) >> 16;
}

// ---- kernels -------------------------------------------------------------
// score: each wave handles 4 rows; 16 lanes per row, 4x float4 per lane.
// Reduction = 4 shfl_xor levels within 16-lane groups (2 DS ops/row vs 12
// for the old 64-lane tree). fp64 accumulate; ranking is monotone in the
// raw dot -> no norm, no tanh here.
__global__ void __launch_bounds__(256) score_kernel(
        const float* __restrict__ x, const float* __restrict__ w,
        unsigned long long* __restrict__ key64, int* __restrict__ hist) {
    const int t    = threadIdx.x;
    const int i    = t & 15;                         /* lane within row-group  */
    const int g    = (t & 63) >> 4;                  /* row-group within wave  */
    const int wid  = (blockIdx.x << 2) + (t >> 6);   /* global wave id         */
    const int row  = (wid << 2) + g;                 /* 4 rows per wave        */
    const float4* xr = (const float4*)(x + (size_t)row * N_FEAT);
    const float4* wr = (const float4*)w;
    double acc = 0.0;
#pragma unroll
    for (int j = 0; j < 4; ++j) {
        float4 xv = xr[i + 16 * j];
        float4 wv = wr[i + 16 * j];
        acc += (double)xv.x * (double)wv.x + (double)xv.y * (double)wv.y +
               (double)xv.z * (double)wv.z + (double)xv.w * (double)wv.w;
    }
#pragma unroll
    for (int m = 8; m >= 1; m >>= 1) acc += __shfl_xor(acc, m, 16);
    if (i == 0) {
        key64[row] = descKey(acc);
        atomicAdd(&hist[bucketOfFloat((float)acc)], 1);
    }
}

// chunked scan: block c scans its 256 bins into chunk-LOCAL exclusive
// prefixes (-> start[]); last-arriving block scans the 256 chunk totals into
// chunkOff[]. Block 0 additionally computes ||w|| in fp64.
__global__ void __launch_bounds__(256) scan_kernel(const int* __restrict__ hist,
                                                   const float* __restrict__ w,
                                                   double* __restrict__ normp,
                                                   int* __restrict__ start,
                                                   int* __restrict__ chunkSums,
                                                   int* __restrict__ chunkOff,
                                                   int* __restrict__ counter) {
    __shared__ int s[256];
    __shared__ double sd[256];
    __shared__ int lastFlag;
    int c = blockIdx.x, t = threadIdx.x;
    if (c == 0) {                       /* ||w|| reduction, fp64 */
        double v = (double)w[t];
        sd[t] = v * v;
        __syncthreads();
        for (int off = 128; off > 0; off >>= 1) {
            if (t < off) sd[t] += sd[t + off];
            __syncthreads();
        }
        if (t == 0) normp[0] = sqrt(sd[0]);
    }
    int v = hist[c * 256 + t];
    s[t] = v;
    __syncthreads();
    for (int off = 1; off < 256; off <<= 1) {
        int add = (t >= off) ? s[t - off] : 0;
        __syncthreads();
        s[t] += add;
        __syncthreads();
    }
    start[c * 256 + t] = s[t] - v; /* chunk-local exclusive prefix */
    if (t == 0) {
        atomicExch(&chunkSums[c], s[255]);   /* device-scope publish */
        __threadfence();
        int old = atomicAdd(counter, 1);
        lastFlag = (old == NCHUNK - 1);
    }
    __syncthreads();
    if (!lastFlag) return;
    int wsum = atomicAdd(&chunkSums[t], 0);  /* device-coherent read */
    __syncthreads();
    s[t] = wsum;
    __syncthreads();
    for (int off = 1; off < 256; off <<= 1) {
        int add = (t >= off) ? s[t - off] : 0;
        __syncthreads();
        s[t] += add;
        __syncthreads();
    }
    chunkOff[t] = s[t] - wsum; /* global exclusive offset of chunk t */
}

// scatter nodes to their bucket's slot range; consumes start[] via atomicAdd
__global__ void scatter_kernel(const unsigned long long* __restrict__ key64,
                               int* __restrict__ start,
                               const int* __restrict__ chunkOff,
                               unsigned long long* __restrict__ slotKey,
                               int* __restrict__ slotIdx) {
    int i = blockIdx.x * blockDim.x + threadIdx.x;
    if (i >= N_NODES) return;
    unsigned long long k = key64[i];
    int b = (int)bucketOfFloat((float)invKey(k));
    int pos = atomicAdd(&start[b], 1) + chunkOff[b >> 8];
    slotKey[pos] = k;
    slotIdx[pos] = i;
}

// exact rank within bucket via fp64 key + index tie-break.
// post-scatter start[b]+chunkOff == bucket end; begin = end - hist[b].
// buckets entirely below the cutoff (st >= K) short-circuit to mapping=-1.
__global__ void rank_kernel(const unsigned long long* __restrict__ slotKey,
                            const int* __restrict__ slotIdx,
                            const int* __restrict__ start, const int* __restrict__ hist,
                            const int* __restrict__ chunkOff,
                            float* __restrict__ mappingF, int* __restrict__ perm,
                            float* __restrict__ selDot) {
    int s = blockIdx.x * blockDim.x + threadIdx.x;
    if (s >= N_NODES) return;
    unsigned long long myKey = slotKey[s];
    int i = slotIdx[s];
    float df = (float)invKey(myKey);
    int b = (int)bucketOfFloat(df);
    int end = start[b] + chunkOff[b >> 8];
    int cnt = hist[b];
    int st = end - cnt;
    if (st >= K_SEL) {                        /* whole bucket below cutoff */
        mappingF[i] = -1.0f;
        return;
    }
    int rank = 0;
    if (cnt > 1) {
        for (int q = st; q < end; ++q) {
            unsigned long long k = slotKey[q];
            if (k < myKey || (k == myKey && slotIdx[q] < i)) ++rank;
        }
    }
    int p = st + rank;
    if (p < K_SEL) {
        mappingF[i] = (float)p;
        perm[p] = i;
        selDot[p] = df;
    } else {
        mappingF[i] = -1.0f;
    }
}

// fused output: blocks [0,GATHER_BLOCKS) gather+gate x rows (tanh here, fp32,
// selected rows only); blocks [GATHER_BLOCKS,...) remap edges, 4/thread int4
__global__ void out_kernel(const float* __restrict__ x, const int* __restrict__ perm,
                           const float* __restrict__ selDot,
                           const double* __restrict__ normp,
                           const int* __restrict__ ei,
                           const float* __restrict__ mappingF,
                           float* __restrict__ out) {
    if (blockIdx.x < GATHER_BLOCKS) {
        int tid = blockIdx.x * 256 + threadIdx.x;
        int r = tid >> 6;
        int c = (tid & 63) << 2;
        int src = perm[r];
        float sc = tanhf(selDot[r] / (float)normp[0]);
        float4 v = *(const float4*)(x + (size_t)src * N_FEAT + c);
        floatx4 o;
        o.x = v.x * sc; o.y = v.y * sc; o.z = v.z * sc; o.w = v.w * sc;
        __builtin_nontemporal_store(o, (floatx4*)(out + (size_t)r * N_FEAT + c));
    } else {
        int tid = (blockIdx.x - GATHER_BLOCKS) * 256 + threadIdx.x;
        int e = tid << 2;
        intx4 a = __builtin_nontemporal_load((const intx4*)(ei + e));
        intx4 b = __builtin_nontemporal_load((const intx4*)(ei + N_EDGES + e));
        float* oeu = out + (size_t)K_SEL * N_FEAT;
        float* oev = oeu + N_EDGES;
        float m0 = mappingF[a.x], m1 = mappingF[a.y];
        float m2 = mappingF[a.z], m3 = mappingF[a.w];
        float n0 = mappingF[b.x], n1 = mappingF[b.y];
        float n2 = mappingF[b.z], n3 = mappingF[b.w];
        floatx4 ou, ov;
        bool v0 = (m0 >= 0.0f) && (n0 >= 0.0f);
        bool v1 = (m1 >= 0.0f) && (n1 >= 0.0f);
        bool v2 = (m2 >= 0.0f) && (n2 >= 0.0f);
        bool v3 = (m3 >= 0.0f) && (n3 >= 0.0f);
        ou.x = v0 ? m0 : -1.0f; ov.x = v0 ? n0 : -1.0f;
        ou.y = v1 ? m1 : -1.0f; ov.y = v1 ? n1 : -1.0f;
        ou.z = v2 ? m2 : -1.0f; ov.z = v2 ? n2 : -1.0f;
        ou.w = v3 ? m3 : -1.0f; ov.w = v3 ? n3 : -1.0f;
        __builtin_nontemporal_store(ou, (floatx4*)(oeu + e));
        __builtin_nontemporal_store(ov, (floatx4*)(oev + e));
    }
}

// ---- launch --------------------------------------------------------------
extern "C" void kernel_launch(void* const* d_in, const int* in_sizes, int n_in,
                              void* d_out, int out_size, void* d_ws, size_t ws_size,
                              hipStream_t stream) {
    const float* x  = (const float*)d_in[0];
    const int*   ei = (const int*)d_in[1];
    const float* w  = (const float*)d_in[2];
    float* out = (float*)d_out;

    char* p = (char*)d_ws;
    double* d_norm = (double*)p;                          p += 16;
    unsigned long long* key64   = (unsigned long long*)p; p += (size_t)N_NODES * 8;
    unsigned long long* slotKey = (unsigned long long*)p; p += (size_t)N_NODES * 8;
    float* mappingF = (float*)p; p += (size_t)N_NODES * 4;
    int*   slotIdx  = (int*)p;   p += (size_t)N_NODES * 4;
    int*   perm     = (int*)p;   p += (size_t)K_SEL * 4;
    float* selDot   = (float*)p; p += (size_t)K_SEL * 4;
    int*   hist     = (int*)p;   p += (size_t)NBUCKET * 4;
    int*   counter  = (int*)p;   p += 16;                 /* adjacent to hist */
    int*   start    = (int*)p;   p += (size_t)NBUCKET * 4;
    int*   chunkSums= (int*)p;   p += (size_t)NCHUNK * 4;
    int*   chunkOff = (int*)p;   p += (size_t)NCHUNK * 4;

    /* zero hist + scan counter in one async fill (graph-capture safe) */
    hipMemsetAsync(hist, 0, (size_t)NBUCKET * 4 + 16, stream);

    score_kernel<<<N_NODES / 16, 256, 0, stream>>>(x, w, key64, hist);

    scan_kernel<<<NCHUNK, 256, 0, stream>>>(hist, w, d_norm, start, chunkSums,
                                            chunkOff, counter);

    int node_blocks = (N_NODES + 255) / 256;
    scatter_kernel<<<node_blocks, 256, 0, stream>>>(key64, start, chunkOff,
                                                    slotKey, slotIdx);

    rank_kernel<<<node_blocks, 256, 0, stream>>>(slotKey, slotIdx, start, hist,
                                                 chunkOff, mappingF, perm, selDot);

    out_kernel<<<GATHER_BLOCKS + EDGE_BLOCKS, 256, 0, stream>>>(x, perm, selDot, d_norm,
                                                                ei, mappingF, out);
}

// Round 4
// 335.143 us; speedup vs baseline: 7.7220x; 1.0075x over previous
//
#include <hip/hip_runtime.h>
#include <math.h>

#define N_NODES 100000
#define N_FEAT  256
#define K_SEL   50000
#define N_EDGES 3200000
#define NBUCKET 65536
#define NCHUNK  256                         /* NBUCKET / 256 bins per chunk */

#define GATHER_BLOCKS (K_SEL / 4)           /* 4 rows (64 lanes ea) per 256-thr block */
#define EDGE_BLOCKS   (N_EDGES / (4 * 256)) /* 4 edges per thread */

typedef float __attribute__((ext_vector_type(4))) floatx4;
typedef int   __attribute__((ext_vector_type(4))) intx4;

// ---- key encodings -------------------------------------------------------
// ascending uint64 key == descending z, so stable-ascending == top_k order
__device__ __forceinline__ unsigned long long descKey(double z) {
    unsigned long long u = (unsigned long long)__double_as_longlong(z);
    unsigned long long a = (u >> 63) ? ~u : (u | 0x8000000000000000ULL);
    return ~a;
}

// exact inverse of descKey (bit-exact roundtrip, finite values)
__device__ __forceinline__ double invKey(unsigned long long k) {
    unsigned long long a = ~k;
    unsigned long long u = (a >> 63) ? (a & 0x7FFFFFFFFFFFFFFFULL) : ~a;
    return __longlong_as_double((long long)u);
}

__device__ __forceinline__ unsigned int bucketOfFloat(float zf) {
    unsigned int u = __float_as_uint(zf);
    unsigned int a = (u >> 31) ? ~u : (u | 0x80000000u);
    return (~a) >> 16;
}

__device__ __forceinline__ double dot4d(float4 a, float4 b) {
    return (double)a.x * (double)b.x + (double)a.y * (double)b.y +
           (double)a.z * (double)b.z + (double)a.w * (double)b.w;
}

// ---- kernels -------------------------------------------------------------
// score: 4 rows per wave. Each row is one CONTIGUOUS 64-lane float4 load
// (4 independent loads -> 4 independent fp64 accumulators: ILP hides VMEM
// latency; no serial load chain as in the R3 regression).  Reduction:
// butterfly d=16,32 per acc (6 fp64 shuffles stay), group-select, butterfly
// d=1,2,4,8 -> 12 fp64 shuffles per 4 rows (6 DS ops/row vs 24 in R1).
__global__ void __launch_bounds__(256) score_kernel(
        const float* __restrict__ x, const float* __restrict__ w,
        unsigned long long* __restrict__ key64, int* __restrict__ hist) {
    const int t    = threadIdx.x;
    const int lane = t & 63;
    const int wid  = (blockIdx.x << 2) + (t >> 6);   /* global wave id  */
    const int row0 = wid << 2;                       /* 4 rows per wave */
    const float4 wv = ((const float4*)w)[lane];
    const float4* xr = (const float4*)(x + (size_t)row0 * N_FEAT);
    /* 4 independent contiguous 1KB wave-loads (back-to-back issue) */
    float4 x0 = xr[lane];
    float4 x1 = xr[64 + lane];
    float4 x2 = xr[128 + lane];
    float4 x3 = xr[192 + lane];
    double a0 = dot4d(x0, wv);
    double a1 = dot4d(x1, wv);
    double a2 = dot4d(x2, wv);
    double a3 = dot4d(x3, wv);
    /* butterfly over distances 16,32: result depends only on lane&15 */
    a0 += __shfl_xor(a0, 16, 64); a0 += __shfl_xor(a0, 32, 64);
    a1 += __shfl_xor(a1, 16, 64); a1 += __shfl_xor(a1, 32, 64);
    a2 += __shfl_xor(a2, 16, 64); a2 += __shfl_xor(a2, 32, 64);
    a3 += __shfl_xor(a3, 16, 64); a3 += __shfl_xor(a3, 32, 64);
    /* group g = lane>>4 adopts acc_g, then reduce within the 16-lane group */
    const int g = lane >> 4;
    double c = (g & 2) ? ((g & 1) ? a3 : a2) : ((g & 1) ? a1 : a0);
    c += __shfl_xor(c, 1, 64);
    c += __shfl_xor(c, 2, 64);
    c += __shfl_xor(c, 4, 64);
    c += __shfl_xor(c, 8, 64);
    if ((lane & 15) == 0) {                          /* lanes 0,16,32,48 */
        int row = row0 + g;
        key64[row] = descKey(c);
        atomicAdd(&hist[bucketOfFloat((float)c)], 1);
    }
}

// chunked scan: block c scans its 256 bins into chunk-LOCAL exclusive
// prefixes (-> start[]); last-arriving block scans the 256 chunk totals into
// chunkOff[]. Block 0 additionally computes ||w|| in fp64.
__global__ void __launch_bounds__(256) scan_kernel(const int* __restrict__ hist,
                                                   const float* __restrict__ w,
                                                   double* __restrict__ normp,
                                                   int* __restrict__ start,
                                                   int* __restrict__ chunkSums,
                                                   int* __restrict__ chunkOff,
                                                   int* __restrict__ counter) {
    __shared__ int s[256];
    __shared__ double sd[256];
    __shared__ int lastFlag;
    int c = blockIdx.x, t = threadIdx.x;
    if (c == 0) {                       /* ||w|| reduction, fp64 */
        double v = (double)w[t];
        sd[t] = v * v;
        __syncthreads();
        for (int off = 128; off > 0; off >>= 1) {
            if (t < off) sd[t] += sd[t + off];
            __syncthreads();
        }
        if (t == 0) normp[0] = sqrt(sd[0]);
    }
    int v = hist[c * 256 + t];
    s[t] = v;
    __syncthreads();
    for (int off = 1; off < 256; off <<= 1) {
        int add = (t >= off) ? s[t - off] : 0;
        __syncthreads();
        s[t] += add;
        __syncthreads();
    }
    start[c * 256 + t] = s[t] - v; /* chunk-local exclusive prefix */
    if (t == 0) {
        atomicExch(&chunkSums[c], s[255]);   /* device-scope publish */
        __threadfence();
        int old = atomicAdd(counter, 1);
        lastFlag = (old == NCHUNK - 1);
    }
    __syncthreads();
    if (!lastFlag) return;
    int wsum = atomicAdd(&chunkSums[t], 0);  /* device-coherent read */
    __syncthreads();
    s[t] = wsum;
    __syncthreads();
    for (int off = 1; off < 256; off <<= 1) {
        int add = (t >= off) ? s[t - off] : 0;
        __syncthreads();
        s[t] += add;
        __syncthreads();
    }
    chunkOff[t] = s[t] - wsum; /* global exclusive offset of chunk t */
}

// scatter nodes to their bucket's slot range; consumes start[] via atomicAdd
__global__ void scatter_kernel(const unsigned long long* __restrict__ key64,
                               int* __restrict__ start,
                               const int* __restrict__ chunkOff,
                               unsigned long long* __restrict__ slotKey,
                               int* __restrict__ slotIdx) {
    int i = blockIdx.x * blockDim.x + threadIdx.x;
    if (i >= N_NODES) return;
    unsigned long long k = key64[i];
    int b = (int)bucketOfFloat((float)invKey(k));
    int pos = atomicAdd(&start[b], 1) + chunkOff[b >> 8];
    slotKey[pos] = k;
    slotIdx[pos] = i;
}

// exact rank within bucket via fp64 key + index tie-break.
// post-scatter start[b]+chunkOff == bucket end; begin = end - hist[b].
// buckets entirely below the cutoff (st >= K) short-circuit to mapping=-1.
__global__ void rank_kernel(const unsigned long long* __restrict__ slotKey,
                            const int* __restrict__ slotIdx,
                            const int* __restrict__ start, const int* __restrict__ hist,
                            const int* __restrict__ chunkOff,
                            float* __restrict__ mappingF, int* __restrict__ perm,
                            float* __restrict__ selDot) {
    int s = blockIdx.x * blockDim.x + threadIdx.x;
    if (s >= N_NODES) return;
    unsigned long long myKey = slotKey[s];
    int i = slotIdx[s];
    float df = (float)invKey(myKey);
    int b = (int)bucketOfFloat(df);
    int end = start[b] + chunkOff[b >> 8];
    int cnt = hist[b];
    int st = end - cnt;
    if (st >= K_SEL) {                        /* whole bucket below cutoff */
        mappingF[i] = -1.0f;
        return;
    }
    int rank = 0;
    if (cnt > 1) {
        for (int q = st; q < end; ++q) {
            unsigned long long k = slotKey[q];
            if (k < myKey || (k == myKey && slotIdx[q] < i)) ++rank;
        }
    }
    int p = st + rank;
    if (p < K_SEL) {
        mappingF[i] = (float)p;
        perm[p] = i;
        selDot[p] = df;
    } else {
        mappingF[i] = -1.0f;
    }
}

// fused output: blocks [0,GATHER_BLOCKS) gather+gate x rows (tanh here, fp32,
// selected rows only); blocks [GATHER_BLOCKS,...) remap edges, 4/thread int4
__global__ void out_kernel(const float* __restrict__ x, const int* __restrict__ perm,
                           const float* __restrict__ selDot,
                           const double* __restrict__ normp,
                           const int* __restrict__ ei,
                           const float* __restrict__ mappingF,
                           float* __restrict__ out) {
    if (blockIdx.x < GATHER_BLOCKS) {
        int tid = blockIdx.x * 256 + threadIdx.x;
        int r = tid >> 6;
        int c = (tid & 63) << 2;
        int src = perm[r];
        float sc = tanhf(selDot[r] / (float)normp[0]);
        float4 v = *(const float4*)(x + (size_t)src * N_FEAT + c);
        floatx4 o;
        o.x = v.x * sc; o.y = v.y * sc; o.z = v.z * sc; o.w = v.w * sc;
        __builtin_nontemporal_store(o, (floatx4*)(out + (size_t)r * N_FEAT + c));
    } else {
        int tid = (blockIdx.x - GATHER_BLOCKS) * 256 + threadIdx.x;
        int e = tid << 2;
        intx4 a = __builtin_nontemporal_load((const intx4*)(ei + e));
        intx4 b = __builtin_nontemporal_load((const intx4*)(ei + N_EDGES + e));
        float* oeu = out + (size_t)K_SEL * N_FEAT;
        float* oev = oeu + N_EDGES;
        float m0 = mappingF[a.x], m1 = mappingF[a.y];
        float m2 = mappingF[a.z], m3 = mappingF[a.w];
        float n0 = mappingF[b.x], n1 = mappingF[b.y];
        float n2 = mappingF[b.z], n3 = mappingF[b.w];
        floatx4 ou, ov;
        bool v0 = (m0 >= 0.0f) && (n0 >= 0.0f);
        bool v1 = (m1 >= 0.0f) && (n1 >= 0.0f);
        bool v2 = (m2 >= 0.0f) && (n2 >= 0.0f);
        bool v3 = (m3 >= 0.0f) && (n3 >= 0.0f);
        ou.x = v0 ? m0 : -1.0f; ov.x = v0 ? n0 : -1.0f;
        ou.y = v1 ? m1 : -1.0f; ov.y = v1 ? n1 : -1.0f;
        ou.z = v2 ? m2 : -1.0f; ov.z = v2 ? n2 : -1.0f;
        ou.w = v3 ? m3 : -1.0f; ov.w = v3 ? n3 : -1.0f;
        __builtin_nontemporal_store(ou, (floatx4*)(oeu + e));
        __builtin_nontemporal_store(ov, (floatx4*)(oev + e));
    }
}

// ---- launch --------------------------------------------------------------
extern "C" void kernel_launch(void* const* d_in, const int* in_sizes, int n_in,
                              void* d_out, int out_size, void* d_ws, size_t ws_size,
                              hipStream_t stream) {
    const float* x  = (const float*)d_in[0];
    const int*   ei = (const int*)d_in[1];
    const float* w  = (const float*)d_in[2];
    float* out = (float*)d_out;

    char* p = (char*)d_ws;
    double* d_norm = (double*)p;                          p += 16;
    unsigned long long* key64   = (unsigned long long*)p; p += (size_t)N_NODES * 8;
    unsigned long long* slotKey = (unsigned long long*)p; p += (size_t)N_NODES * 8;
    float* mappingF = (float*)p; p += (size_t)N_NODES * 4;
    int*   slotIdx  = (int*)p;   p += (size_t)N_NODES * 4;
    int*   perm     = (int*)p;   p += (size_t)K_SEL * 4;
    float* selDot   = (float*)p; p += (size_t)K_SEL * 4;
    int*   hist     = (int*)p;   p += (size_t)NBUCKET * 4;
    int*   counter  = (int*)p;   p += 16;                 /* adjacent to hist */
    int*   start    = (int*)p;   p += (size_t)NBUCKET * 4;
    int*   chunkSums= (int*)p;   p += (size_t)NCHUNK * 4;
    int*   chunkOff = (int*)p;   p += (size_t)NCHUNK * 4;

    /* zero hist + scan counter in one async fill (graph-capture safe) */
    hipMemsetAsync(hist, 0, (size_t)NBUCKET * 4 + 16, stream);

    score_kernel<<<N_NODES / 16, 256, 0, stream>>>(x, w, key64, hist);

    scan_kernel<<<NCHUNK, 256, 0, stream>>>(hist, w, d_norm, start, chunkSums,
                                            chunkOff, counter);

    int node_blocks = (N_NODES + 255) / 256;
    scatter_kernel<<<node_blocks, 256, 0, stream>>>(key64, start, chunkOff,
                                                    slotKey, slotIdx);

    rank_kernel<<<node_blocks, 256, 0, stream>>>(slotKey, slotIdx, start, hist,
                                                 chunkOff, mappingF, perm, selDot);

    out_kernel<<<GATHER_BLOCKS + EDGE_BLOCKS, 256, 0, stream>>>(x, perm, selDot, d_norm,
                                                                ei, mappingF, out);
}